// Round 2
// baseline (770.207 us; speedup 1.0000x reference)
//
#include <hip/hip_runtime.h>
#include <cstdint>
#include <cstddef>

// ---------------------------------------------------------------------------
// Llama decoder layer, MI355X.  B=1, T=2048, D=2048, FF=8192, NH=32, NKV=8,
// HD=64.  bf16 MFMA, fp32 accumulate.
// out = h2 + mlp(h2) + x0, where h2 = rms(h1 + attn(h1)), h1 = rms(x0).
//
// Round 7: MLP GEMMs (gate/up/down) moved to a 256x256-tile 8-phase kernel
// (gemm256): BK=64, 8 waves (512 thr), 128 KiB double-buffered LDS,
// per-phase {ds_read || stage half-tile -> s_barrier -> lgkmcnt(0) ->
// setprio(1) 16xMFMA setprio(0) -> s_barrier}, counted vmcnt(4) once per
// K-tile (never drained to 0 mid-loop).  A-halves staged 1 tile ahead
// (p0/p1), B-halves 2 tiles ahead (p2/p3, into the released region of the
// buffer being consumed).  XOR k-chunk swizzle as in the 128^2 kernel.
// QKV (rope epi) and wo stay on the old 128^2 gemm_bt.
// ---------------------------------------------------------------------------

typedef __attribute__((ext_vector_type(8))) short short8;   // 8 x bf16
typedef __attribute__((ext_vector_type(4))) float f32x4;
typedef __attribute__((ext_vector_type(16))) float f32x16;

typedef __attribute__((address_space(1))) const void gvoid_t;  // global
typedef __attribute__((address_space(3))) void lvoid_t;        // LDS

__device__ inline unsigned short f2b(float f) {   // fp32 -> bf16 (RNE)
  unsigned int u = __float_as_uint(f);
  u += 0x7fffu + ((u >> 16) & 1u);
  return (unsigned short)(u >> 16);
}
__device__ inline float b2f(unsigned short s) {
  return __uint_as_float((unsigned int)s << 16);
}
__device__ inline unsigned int pkbf(float lo, float hi) {  // 2xf32 -> packed bf16
  unsigned int r;
  asm("v_cvt_pk_bf16_f32 %0, %1, %2" : "=v"(r) : "v"(lo), "v"(hi));
  return r;
}

#define SBAR()                                  \
  do {                                          \
    asm volatile("" ::: "memory");              \
    __builtin_amdgcn_s_barrier();               \
    asm volatile("" ::: "memory");              \
  } while (0)

// ---------------------------------------------------------------------------
// Cast + transpose:  W fp32 [R][ldW]  ->  Wt bf16 [ldW-cols][R]
// ---------------------------------------------------------------------------
__global__ __launch_bounds__(256) void transpose_cast(
    const float* __restrict__ W, unsigned short* __restrict__ Wt,
    int R, int ldW) {
  __shared__ unsigned short s[32 * 36];
  const int r0 = blockIdx.y * 32, c0 = blockIdx.x * 32;
  const int tr = threadIdx.x >> 3, tc = (threadIdx.x & 7) << 2;
  const float4 v = *(const float4*)(W + (size_t)(r0 + tr) * ldW + c0 + tc);
  s[tr * 36 + tc + 0] = f2b(v.x);
  s[tr * 36 + tc + 1] = f2b(v.y);
  s[tr * 36 + tc + 2] = f2b(v.z);
  s[tr * 36 + tc + 3] = f2b(v.w);
  __syncthreads();
  ushort4 o;
  o.x = s[(tc + 0) * 36 + tr];
  o.y = s[(tc + 1) * 36 + tr];
  o.z = s[(tc + 2) * 36 + tr];
  o.w = s[(tc + 3) * 36 + tr];
  *(ushort4*)(Wt + (size_t)(c0 + tr) * R + r0 + tc) = o;
}

// ---------------------------------------------------------------------------
// RMSNorm (one block per row of 2048) -> bf16.
// ---------------------------------------------------------------------------
__global__ __launch_bounds__(256) void rmsnorm(
    const float* __restrict__ X, const float* __restrict__ g,
    unsigned short* __restrict__ ob) {
  const int row = blockIdx.x;
  const float* x = X + (size_t)row * 2048;
  float ss = 0.f;
  for (int i = threadIdx.x; i < 2048; i += 256) { float v = x[i]; ss += v * v; }
  for (int off = 32; off; off >>= 1) ss += __shfl_down(ss, off, 64);
  __shared__ float red[4];
  if ((threadIdx.x & 63) == 0) red[threadIdx.x >> 6] = ss;
  __syncthreads();
  const float tot = red[0] + red[1] + red[2] + red[3];
  const float r = rsqrtf(tot * (1.f / 2048.f) + 1e-5f);
  for (int i = threadIdx.x; i < 2048; i += 256)
    ob[(size_t)row * 2048 + i] = f2b(x[i] * g[i] * r);
}

// ---------------------------------------------------------------------------
// out = x0 + b2f(h2), vectorized x4.  Pre-fill for the split-K down-proj.
// ---------------------------------------------------------------------------
__global__ __launch_bounds__(256) void add_res(
    const unsigned short* __restrict__ h2, const float* __restrict__ x,
    float* __restrict__ out) {
  const int i = blockIdx.x * 256 + threadIdx.x;
  const ushort4 h = ((const ushort4*)h2)[i];
  const float4 xv = ((const float4*)x)[i];
  float4 o;
  o.x = xv.x + b2f(h.x); o.y = xv.y + b2f(h.y);
  o.z = xv.z + b2f(h.z); o.w = xv.w + b2f(h.w);
  ((float4*)out)[i] = o;
}

// ---------------------------------------------------------------------------
// GEMM (128x128, 4 waves): kept for QKV (rope epi 7) and wo (epi 1).
// ---------------------------------------------------------------------------
__global__ __launch_bounds__(256, 2) void gemm_bt(
    const unsigned short* __restrict__ A, const unsigned short* __restrict__ Bt,
    float* Cf, unsigned short* Cb,
    const unsigned short* add1b, const float* add2,
    int N, int Kfull, int Kchunk, int epi, int Tld,
    unsigned short* Cb2, unsigned short* Cb3) {
  __shared__ unsigned short As[128 * 64];
  __shared__ unsigned short Bs[128 * 64];
  const int tid = threadIdx.x;
  const int wave = tid >> 6, lane = tid & 63;
  const int quad = lane >> 4, l16 = lane & 15;
  const int m0 = blockIdx.y * 128, n0 = blockIdx.x * 128;
  const int wr = (wave >> 1) * 64, wc = (wave & 1) * 64;
  const int Ks = blockIdx.z * Kchunk, Ke = Ks + Kchunk;

  f32x4 acc[4][4] = {};

  for (int k0 = Ks; k0 < Ke; k0 += 64) {
#pragma unroll
    for (int p = 0; p < 4; ++p) {
      const int idx = p * 256 + tid;
      const int row = idx >> 3;
      const int kc = ((idx & 7) ^ (row & 7)) * 8;
      const unsigned short* gA = A + (size_t)(m0 + row) * Kfull + k0 + kc;
      const unsigned short* gB = Bt + (size_t)(n0 + row) * Kfull + k0 + kc;
      unsigned short* lA = As + (size_t)(p * 256 + wave * 64) * 8;
      unsigned short* lB = Bs + (size_t)(p * 256 + wave * 64) * 8;
      __builtin_amdgcn_global_load_lds((gvoid_t*)gA, (lvoid_t*)lA, 16, 0, 0);
      __builtin_amdgcn_global_load_lds((gvoid_t*)gB, (lvoid_t*)lB, 16, 0, 0);
    }
    __syncthreads();

#pragma unroll
    for (int ks = 0; ks < 2; ++ks) {
      short8 af[4], bf[4];
#pragma unroll
      for (int i = 0; i < 4; ++i) {
        const int row = wr + i * 16 + l16;
        af[i] = *(const short8*)(As + row * 64 +
                                 (((ks << 2) | quad) ^ (row & 7)) * 8);
      }
#pragma unroll
      for (int j = 0; j < 4; ++j) {
        const int row = wc + j * 16 + l16;
        bf[j] = *(const short8*)(Bs + row * 64 +
                                 (((ks << 2) | quad) ^ (row & 7)) * 8);
      }
#pragma unroll
      for (int i = 0; i < 4; ++i)
#pragma unroll
        for (int j = 0; j < 4; ++j)
          acc[i][j] = __builtin_amdgcn_mfma_f32_16x16x32_bf16(
              af[i], bf[j], acc[i][j], 0, 0, 0);
    }
    __syncthreads();
  }

  if (epi == 7 && n0 >= 2560) {   // transposed V store (block-uniform)
#pragma unroll
    for (int i = 0; i < 4; ++i)
#pragma unroll
      for (int j = 0; j < 4; ++j) {
        const int row = m0 + wr + i * 16 + quad * 4;
        const int col = n0 + wc + j * 16 + l16 - 2560;
        ushort4 o;
        o.x = f2b(acc[i][j][0]); o.y = f2b(acc[i][j][1]);
        o.z = f2b(acc[i][j][2]); o.w = f2b(acc[i][j][3]);
        *(ushort4*)(Cb3 + (size_t)col * Tld + row) = o;
      }
    return;
  }

#pragma unroll
  for (int i = 0; i < 4; ++i)
#pragma unroll
    for (int j = 0; j < 4; ++j) {
      const int rowb = m0 + wr + i * 16 + quad * 4;
      const int col = n0 + wc + j * 16 + l16;
      float invf = 0.f, sgn = 0.f;
      if (epi == 7) {
        const int ip = (col & 63) >> 1;
        invf = __expf(-(float)ip * 0.28782313662f); // 10000^(-ip/32)
        sgn = (col & 1) ? 1.f : -1.f;
      }
#pragma unroll
      for (int r = 0; r < 4; ++r) {
        const size_t idx = (size_t)(rowb + r) * N + col;
        const float v = acc[i][j][r];
        const float p = __shfl_xor(v, 1, 64);
        if (epi == 1) {
          Cf[idx] = v + b2f(add1b[idx]);
        } else if (epi == 3) {
          const float gt = b2f(add1b[idx]);
          Cb[idx] = f2b(gt / (1.f + __expf(-gt)) * v);
        } else if (epi == 4) {
          Cb[idx] = f2b(v);
        } else if (epi == 8) {
          atomicAdd(&Cf[idx], v);
        } else {  // 7: rope -> q or k (block-uniform region)
          float sn, cs;
          __sincosf((float)(rowb + r) * invf, &sn, &cs);
          const unsigned short o = f2b(v * cs + sgn * p * sn);
          if (col < 2048)
            Cb[(size_t)(rowb + r) * 2048 + col] = o;
          else
            Cb2[(size_t)(rowb + r) * 512 + col - 2048] = o;
        }
      }
    }
}

// ---------------------------------------------------------------------------
// gemm256: 256x256 tile, BK=64, 8 waves (2M x 4N, 128x64 out each), 8-phase
// schedule with counted vmcnt.  A[M][K] * Bt[N][K]^T, bf16 in / fp32 acc.
//
// Phase (of K-tile u): p=(a<<1|b) computes C-quadrant (a=i-half, b=j-half),
// 16 MFMA (4i x 2j x 2ks).  ds_reads: p0: A[a0](8)+B[b0](4); p1: B[b1](4);
// p2: A[a1](8); p3: none.  LDS liveness: A last read p2, B last read p1.
// Staging (1 half-tile = 2 global_load_lds/thread per phase):
//   p0: Ah0(u+1)->As[~u]   p1: Ah1(u+1)->As[~u]     (A region free since
//       p2(u-1))
//   p2: Bh0(u+2)->Bs[u&1]  p3: Bh1(u+2)->Bs[u&1]    (B region free since
//       p1(u))
// Wait: end of p3, s_waitcnt vmcnt(4) (allows the 2 B-halves of u+2 to stay
// in flight) -> barrier -> p0(u+1) ds_reads safe.  vmcnt(0) only for the
// final prefetch; skipped on the last tile.
// ---------------------------------------------------------------------------
__device__ __forceinline__ void stage_half(
    const unsigned short* __restrict__ G, int ldg, unsigned short* L,
    int k0, int wave) {
  const int lane = threadIdx.x & 63;
#pragma unroll
  for (int l = 0; l < 2; ++l) {
    const int idx = l * 512 + wave * 64 + lane;   // 0..1023 -> 128 rows x 8 ch
    const int row = idx >> 3;
    const int kc = ((idx & 7) ^ (row & 7)) << 3;  // XOR k-chunk swizzle
    const unsigned short* g = G + (size_t)row * ldg + k0 + kc;
    unsigned short* lp = L + (size_t)(l * 512 + wave * 64) * 8;
    __builtin_amdgcn_global_load_lds((gvoid_t*)g, (lvoid_t*)lp, 16, 0, 0);
  }
}

__global__ __launch_bounds__(512, 2) void gemm256(
    const unsigned short* __restrict__ A, const unsigned short* __restrict__ Bt,
    float* Cf, unsigned short* Cb, const unsigned short* add1b,
    int N, int Kfull, int Kchunk, int epi) {
  __shared__ unsigned short As[2][256 * 64];   // 64 KB
  __shared__ unsigned short Bs[2][256 * 64];   // 64 KB
  const int tid = threadIdx.x;
  const int wave = tid >> 6, lane = tid & 63;
  const int quad = lane >> 4, l16 = lane & 15;
  const int wm = wave >> 2, wn = wave & 3;     // 2 x 4 wave grid
  const int m0 = blockIdx.y * 256, n0 = blockIdx.x * 256;
  const int Ks = blockIdx.z * Kchunk;
  const int NT = Kchunk >> 6;

  const unsigned short* Ag = A + (size_t)m0 * Kfull + Ks;
  const unsigned short* Bg = Bt + (size_t)n0 * Kfull + Ks;
  const size_t hstep = (size_t)128 * Kfull;

  f32x4 acc[8][4] = {};

  // Prologue: A(0) -> As[0]; B(0) -> Bs[0]; B(1) -> Bs[1].  (12 loads/thread)
  stage_half(Ag, Kfull, &As[0][0], 0, wave);
  stage_half(Ag + hstep, Kfull, &As[0][128 * 64], 0, wave);
  stage_half(Bg, Kfull, &Bs[0][0], 0, wave);
  stage_half(Bg + hstep, Kfull, &Bs[0][128 * 64], 0, wave);
  if (NT > 1) {
    stage_half(Bg, Kfull, &Bs[1][0], 64, wave);
    stage_half(Bg + hstep, Kfull, &Bs[1][128 * 64], 64, wave);
    asm volatile("s_waitcnt vmcnt(4)" ::: "memory");
  } else {
    asm volatile("s_waitcnt vmcnt(0)" ::: "memory");
  }
  SBAR();

  const int cbank = ((quad) ^ (l16 & 7)) * 8;  // chunk byte-pattern helper

  for (int u = 0; u < NT; ++u) {
    const unsigned short* Asb = &As[u & 1][0];
    const unsigned short* Bsb = &Bs[u & 1][0];
    unsigned short* Asn = &As[(u + 1) & 1][0];
    unsigned short* Bsn = &Bs[u & 1][0];        // (u+2)&1 == u&1
    const int k1 = (u + 1) << 6, k2 = (u + 2) << 6;

    short8 af[4][2], bf0[2][2], bf1[2][2];

    // ---- phase 0: read A[a0] + B[b0]; stage Ah0(u+1); MFMA (a0,b0) ----
#pragma unroll
    for (int ii = 0; ii < 4; ++ii)
#pragma unroll
      for (int ks = 0; ks < 2; ++ks) {
        const int row = wm * 128 + ii * 16 + l16;
        af[ii][ks] = *(const short8*)(
            Asb + row * 64 + ((((ks << 2) | quad) ^ (l16 & 7)) << 3));
      }
#pragma unroll
    for (int j = 0; j < 2; ++j)
#pragma unroll
      for (int ks = 0; ks < 2; ++ks) {
        const int row = wn * 64 + j * 16 + l16;
        bf0[j][ks] = *(const short8*)(
            Bsb + row * 64 + ((((ks << 2) | quad) ^ (l16 & 7)) << 3));
      }
    if (u + 1 < NT) stage_half(Ag, Kfull, Asn, k1, wave);
    SBAR();
    asm volatile("s_waitcnt lgkmcnt(0)" ::: "memory");
    __builtin_amdgcn_sched_barrier(0);
    __builtin_amdgcn_s_setprio(1);
#pragma unroll
    for (int ii = 0; ii < 4; ++ii)
#pragma unroll
      for (int j = 0; j < 2; ++j)
#pragma unroll
        for (int ks = 0; ks < 2; ++ks)
          acc[ii][j] = __builtin_amdgcn_mfma_f32_16x16x32_bf16(
              af[ii][ks], bf0[j][ks], acc[ii][j], 0, 0, 0);
    __builtin_amdgcn_s_setprio(0);
    SBAR();

    // ---- phase 1: read B[b1]; stage Ah1(u+1); MFMA (a0,b1) ----
#pragma unroll
    for (int j = 0; j < 2; ++j)
#pragma unroll
      for (int ks = 0; ks < 2; ++ks) {
        const int row = wn * 64 + (2 + j) * 16 + l16;
        bf1[j][ks] = *(const short8*)(
            Bsb + row * 64 + ((((ks << 2) | quad) ^ (l16 & 7)) << 3));
      }
    if (u + 1 < NT) stage_half(Ag + hstep, Kfull, Asn + 128 * 64, k1, wave);
    SBAR();
    asm volatile("s_waitcnt lgkmcnt(0)" ::: "memory");
    __builtin_amdgcn_sched_barrier(0);
    __builtin_amdgcn_s_setprio(1);
#pragma unroll
    for (int ii = 0; ii < 4; ++ii)
#pragma unroll
      for (int j = 0; j < 2; ++j)
#pragma unroll
        for (int ks = 0; ks < 2; ++ks)
          acc[ii][2 + j] = __builtin_amdgcn_mfma_f32_16x16x32_bf16(
              af[ii][ks], bf1[j][ks], acc[ii][2 + j], 0, 0, 0);
    __builtin_amdgcn_s_setprio(0);
    SBAR();

    // ---- phase 2: read A[a1]; stage Bh0(u+2); MFMA (a1,b0) ----
#pragma unroll
    for (int ii = 0; ii < 4; ++ii)
#pragma unroll
      for (int ks = 0; ks < 2; ++ks) {
        const int row = wm * 128 + (4 + ii) * 16 + l16;
        af[ii][ks] = *(const short8*)(
            Asb + row * 64 + ((((ks << 2) | quad) ^ (l16 & 7)) << 3));
      }
    if (u + 2 < NT) stage_half(Bg, Kfull, Bsn, k2, wave);
    SBAR();
    asm volatile("s_waitcnt lgkmcnt(0)" ::: "memory");
    __builtin_amdgcn_sched_barrier(0);
    __builtin_amdgcn_s_setprio(1);
#pragma unroll
    for (int ii = 0; ii < 4; ++ii)
#pragma unroll
      for (int j = 0; j < 2; ++j)
#pragma unroll
        for (int ks = 0; ks < 2; ++ks)
          acc[4 + ii][j] = __builtin_amdgcn_mfma_f32_16x16x32_bf16(
              af[ii][ks], bf0[j][ks], acc[4 + ii][j], 0, 0, 0);
    __builtin_amdgcn_s_setprio(0);
    SBAR();

    // ---- phase 3: stage Bh1(u+2); MFMA (a1,b1); counted vmcnt ----
    if (u + 2 < NT) stage_half(Bg + hstep, Kfull, Bsn + 128 * 64, k2, wave);
    SBAR();
    __builtin_amdgcn_s_setprio(1);
#pragma unroll
    for (int ii = 0; ii < 4; ++ii)
#pragma unroll
      for (int j = 0; j < 2; ++j)
#pragma unroll
        for (int ks = 0; ks < 2; ++ks)
          acc[4 + ii][2 + j] = __builtin_amdgcn_mfma_f32_16x16x32_bf16(
              af[ii][ks], bf1[j][ks], acc[4 + ii][2 + j], 0, 0, 0);
    __builtin_amdgcn_s_setprio(0);
    if (u + 2 < NT) {
      asm volatile("s_waitcnt vmcnt(4)" ::: "memory");  // A(u+1)+B(u+1) done
    } else if (u + 1 < NT) {
      asm volatile("s_waitcnt vmcnt(0)" ::: "memory");  // final prefetch
    }
    SBAR();
  }

  // Epilogue.  C/D layout: col = l16, row = quad*4 + r.
#pragma unroll
  for (int i = 0; i < 8; ++i)
#pragma unroll
    for (int j = 0; j < 4; ++j) {
      const int rowb = m0 + wm * 128 + i * 16 + quad * 4;
      const int col = n0 + wn * 64 + j * 16 + l16;
#pragma unroll
      for (int r = 0; r < 4; ++r) {
        const size_t idx = (size_t)(rowb + r) * N + col;
        const float v = acc[i][j][r];
        if (epi == 3) {
          const float gt = b2f(add1b[idx]);
          Cb[idx] = f2b(gt / (1.f + __expf(-gt)) * v);
        } else if (epi == 4) {
          Cb[idx] = f2b(v);
        } else {  // 8: split-K accumulate
          atomicAdd(&Cf[idx], v);
        }
      }
    }
}

// ---------------------------------------------------------------------------
// Flash attention, swapped-QK^T 32x32x16 (unchanged from round 6).
// ---------------------------------------------------------------------------
__global__ __launch_bounds__(256) void flash_attn(
    const unsigned short* __restrict__ Qb, const unsigned short* __restrict__ Kb,
    const unsigned short* __restrict__ Vt, unsigned short* __restrict__ Y,
    int T) {
  const int tid = threadIdx.x;
  const int wave = tid >> 6, lane = tid & 63;
  const int l32 = lane & 31, hi = lane >> 5;
  const int h = blockIdx.y, kvh = h >> 2;
  const int qt = (blockIdx.x + wave * 16) << 5;
  const int qrow = qt + l32;

  short8 qf[4];
#pragma unroll
  for (int ds = 0; ds < 4; ++ds) {
    short8 v = *(const short8*)(Qb + (size_t)qrow * 2048 + h * 64 +
                                ds * 16 + hi * 8);
#pragma unroll
    for (int e = 0; e < 8; ++e)
      v[e] = (short)f2b(b2f((unsigned short)v[e]) * 0.125f);
    qf[ds] = v;
  }

  const unsigned short* Kp = Kb + (size_t)l32 * 512 + kvh * 64 + hi * 8;
  const unsigned short* Vp = Vt + (size_t)(kvh * 64 + l32) * T + hi * 8;

  const int niter = (qt >> 5) + 1;
  float m_i = -3e38f, l_i = 0.f;
  f32x16 o0 = {}, o1 = {};

  short8 kf[4], kfn[4];
#pragma unroll
  for (int ds = 0; ds < 4; ++ds) kf[ds] = *(const short8*)(Kp + ds * 16);

  for (int it = 0; it < niter; ++it) {
    const int k0 = it << 5;
    short8 vf[2][2];
#pragma unroll
    for (int dt = 0; dt < 2; ++dt)
#pragma unroll
      for (int ks = 0; ks < 2; ++ks)
        vf[dt][ks] =
            *(const short8*)(Vp + (size_t)dt * 32 * T + k0 + ks * 16);
    const int kn = (k0 + 32 < 2016) ? k0 + 32 : 2016;
#pragma unroll
    for (int ds = 0; ds < 4; ++ds)
      kfn[ds] = *(const short8*)(Kp + (size_t)kn * 512 + ds * 16);

    f32x16 S = {};
#pragma unroll
    for (int ds = 0; ds < 4; ++ds)
      S = __builtin_amdgcn_mfma_f32_32x32x16_bf16(kf[ds], qf[ds], S, 0, 0, 0);

    float s[16];
#pragma unroll
    for (int r = 0; r < 16; ++r) s[r] = S[r];
    if (k0 == qt) {
#pragma unroll
      for (int r = 0; r < 16; ++r)
        if (((r & 3) + 8 * (r >> 2) + 4 * hi) > l32) s[r] = -3e38f;
    }

    float tmax = s[0];
#pragma unroll
    for (int r = 1; r < 16; ++r) tmax = fmaxf(tmax, s[r]);
    tmax = fmaxf(tmax, __shfl_xor(tmax, 32, 64));

    if (!__all(tmax <= m_i + 8.f)) {
      const float mn = fmaxf(m_i, tmax);
      const float al = __expf(m_i - mn);
#pragma unroll
      for (int r = 0; r < 16; ++r) { o0[r] *= al; o1[r] *= al; }
      l_i *= al;
      m_i = mn;
    }

    float p[16], rs = 0.f;
#pragma unroll
    for (int r = 0; r < 16; ++r) { p[r] = __expf(s[r] - m_i); rs += p[r]; }
    rs += __shfl_xor(rs, 32, 64);
    l_i += rs;

    short8 pf[2];
#pragma unroll
    for (int ks = 0; ks < 2; ++ks) {
      const int rb = ks * 8;
      const unsigned int a0 = pkbf(p[rb + 0], p[rb + 1]);
      const unsigned int a1 = pkbf(p[rb + 2], p[rb + 3]);
      const unsigned int b0 = pkbf(p[rb + 4], p[rb + 5]);
      const unsigned int b1 = pkbf(p[rb + 6], p[rb + 7]);
      const unsigned int t0 = __shfl_xor((int)(hi ? a0 : b0), 32, 64);
      const unsigned int t1 = __shfl_xor((int)(hi ? a1 : b1), 32, 64);
      union { unsigned int u[4]; short8 v; } pu;
      pu.u[0] = hi ? t0 : a0;
      pu.u[1] = hi ? t1 : a1;
      pu.u[2] = hi ? b0 : t0;
      pu.u[3] = hi ? b1 : t1;
      pf[ks] = pu.v;
    }

#pragma unroll
    for (int ks = 0; ks < 2; ++ks) {
      o0 = __builtin_amdgcn_mfma_f32_32x32x16_bf16(vf[0][ks], pf[ks], o0,
                                                   0, 0, 0);
      o1 = __builtin_amdgcn_mfma_f32_32x32x16_bf16(vf[1][ks], pf[ks], o1,
                                                   0, 0, 0);
    }
#pragma unroll
    for (int ds = 0; ds < 4; ++ds) kf[ds] = kfn[ds];
  }

  const float inv = 1.f / l_i;
  unsigned short* Yp = Y + (size_t)qrow * 2048 + h * 64 + hi * 4;
#pragma unroll
  for (int g = 0; g < 4; ++g) {
    ushort4 u0, u1;
    u0.x = f2b(o0[g * 4 + 0] * inv); u0.y = f2b(o0[g * 4 + 1] * inv);
    u0.z = f2b(o0[g * 4 + 2] * inv); u0.w = f2b(o0[g * 4 + 3] * inv);
    *(ushort4*)(Yp + g * 8) = u0;
    u1.x = f2b(o1[g * 4 + 0] * inv); u1.y = f2b(o1[g * 4 + 1] * inv);
    u1.z = f2b(o1[g * 4 + 2] * inv); u1.w = f2b(o1[g * 4 + 3] * inv);
    *(ushort4*)(Yp + 32 + g * 8) = u1;
  }
}

// ---------------------------------------------------------------------------
extern "C" void kernel_launch(void* const* d_in, const int* in_sizes, int n_in,
                              void* d_out, int out_size, void* d_ws,
                              size_t ws_size, hipStream_t stream) {
  const float* x  = (const float*)d_in[0];
  const float* g1 = (const float*)d_in[1];
  const float* wq = (const float*)d_in[2];
  const float* wk = (const float*)d_in[3];
  const float* wv = (const float*)d_in[4];
  const float* wo = (const float*)d_in[5];
  const float* g2 = (const float*)d_in[6];
  const float* wg = (const float*)d_in[7];
  const float* wu = (const float*)d_in[8];
  const float* wd = (const float*)d_in[9];
  float* out = (float*)d_out;

  const int T = 2048, Dm = 2048, FF = 8192;
  char* ws = (char*)d_ws;
  const size_t MB = (size_t)1 << 20;

  unsigned short* wq_t = (unsigned short*)(ws + 0 * MB);    // 8 MB  } contig
  unsigned short* wk_t = (unsigned short*)(ws + 8 * MB);    // 2 MB  } rows
  unsigned short* wv_t = (unsigned short*)(ws + 10 * MB);   // 2 MB  } 0..3071
  unsigned short* wo_t = (unsigned short*)(ws + 12 * MB);   // 8 MB
  unsigned short* wg_t = (unsigned short*)(ws + 20 * MB);   // 32 MB
  unsigned short* wu_t = (unsigned short*)(ws + 52 * MB);   // 32 MB
  unsigned short* h1_b = (unsigned short*)(ws + 84 * MB);   // 8 MB
  unsigned short* h2_b = (unsigned short*)(ws + 92 * MB);   // 8 MB
  float*          x2_f = (float*)(ws + 100 * MB);           // 16 MB (dies early)
  unsigned short* gate = (unsigned short*)(ws + 100 * MB);  // 32 MB (in-place)
  unsigned short* q_b  = (unsigned short*)(ws + 132 * MB);  // 8 MB
  unsigned short* k_b  = (unsigned short*)(ws + 140 * MB);  // 2 MB
  unsigned short* vt_b = (unsigned short*)(ws + 142 * MB);  // 2 MB
  unsigned short* y_b  = (unsigned short*)(ws + 144 * MB);  // 8 MB
  unsigned short* wd_t = (unsigned short*)(ws + 132 * MB);  // 32 MB (after attn)

  // 1. Weight cast+transpose (wd deferred until attn scratch is dead).
  transpose_cast<<<dim3(64, 64), 256, 0, stream>>>(wq, wq_t, Dm, Dm);
  transpose_cast<<<dim3(16, 64), 256, 0, stream>>>(wk, wk_t, Dm, 512);
  transpose_cast<<<dim3(16, 64), 256, 0, stream>>>(wv, wv_t, Dm, 512);
  transpose_cast<<<dim3(64, 64), 256, 0, stream>>>(wo, wo_t, Dm, Dm);
  transpose_cast<<<dim3(256, 64), 256, 0, stream>>>(wg, wg_t, Dm, FF);
  transpose_cast<<<dim3(256, 64), 256, 0, stream>>>(wu, wu_t, Dm, FF);

  // 2. h1 = rms(x0)
  rmsnorm<<<T, 256, 0, stream>>>(x, g1, h1_b);

  // 3. Fused QKV projection (N=3072): rope q -> q_b, rope k -> k_b,
  //    transposed v -> vt_b.
  gemm_bt<<<dim3(24, 16), 256, 0, stream>>>(h1_b, wq_t, nullptr, q_b, nullptr,
                                            nullptr, 3072, Dm, Dm, 7, T, k_b,
                                            vt_b);

  // 4. Attention: 64 q-tiles x 32 heads, 4 independent waves/block.
  flash_attn<<<dim3(16, 32), 256, 0, stream>>>(q_b, k_b, vt_b, y_b, T);

  // 5. x2 = h1 + y @ wo  (epi 1).
  gemm_bt<<<dim3(16, 16), 256, 0, stream>>>(y_b, wo_t, x2_f, nullptr, h1_b,
                                            nullptr, Dm, Dm, Dm, 1, 0, nullptr,
                                            nullptr);

  // 6. wd transpose into the now-dead attention scratch.
  transpose_cast<<<dim3(64, 256), 256, 0, stream>>>(wd, wd_t, FF, Dm);

  // 7. h2 = rms(x2)
  rmsnorm<<<T, 256, 0, stream>>>(x2_f, g2, h2_b);

  // 8. MLP on the 256^2 8-phase kernel: gate (epi 4), up+silu in-place (epi 3).
  gemm256<<<dim3(32, 8), 512, 0, stream>>>(h2_b, wg_t, nullptr, gate, nullptr,
                                           FF, Dm, Dm, 4);
  gemm256<<<dim3(32, 8), 512, 0, stream>>>(h2_b, wu_t, nullptr, gate, gate,
                                           FF, Dm, Dm, 3);

  // 9. out = h2 + x0 (pre-fill), then split-K x4 down-proj atomicAdd.
  add_res<<<(T * Dm / 4) / 256, 256, 0, stream>>>(h2_b, x, out);
  gemm256<<<dim3(8, 8, 4), 512, 0, stream>>>(gate, wd_t, out, nullptr, nullptr,
                                             Dm, FF, FF / 4, 8);
}

// Round 3
// 724.674 us; speedup vs baseline: 1.0628x; 1.0628x over previous
//
#include <hip/hip_runtime.h>
#include <cstdint>
#include <cstddef>

// ---------------------------------------------------------------------------
// Llama decoder layer, MI355X.  B=1, T=2048, D=2048, FF=8192, NH=32, NKV=8,
// HD=64.  bf16 MFMA, fp32 accumulate.
// out = h2 + mlp(h2) + x0, where h2 = rms(h1 + attn(h1)), h1 = rms(x0).
//
// Round 8: gemm256 (8-phase, 1 block/CU) reverted — it regressed (21% MfmaUtil,
// nothing resident to hide the per-tile vmcnt stall).  Back to the proven
// 128^2 / 2-blocks-per-CU structure, plus:
//  - gemm_gu: fused gate+up (3 LDS panels, 48 KB, 32 MFMA per K-step off the
//    same A-frags, in-register silu(g)*u epilogue -> no gate round-trip).
//  - XCD-aware chunked block swizzle (T1) on gemm_bt and gemm_gu.
// ---------------------------------------------------------------------------

typedef __attribute__((ext_vector_type(8))) short short8;   // 8 x bf16
typedef __attribute__((ext_vector_type(4))) float f32x4;
typedef __attribute__((ext_vector_type(16))) float f32x16;

typedef __attribute__((address_space(1))) const void gvoid_t;  // global
typedef __attribute__((address_space(3))) void lvoid_t;        // LDS

__device__ inline unsigned short f2b(float f) {   // fp32 -> bf16 (RNE)
  unsigned int u = __float_as_uint(f);
  u += 0x7fffu + ((u >> 16) & 1u);
  return (unsigned short)(u >> 16);
}
__device__ inline float b2f(unsigned short s) {
  return __uint_as_float((unsigned int)s << 16);
}
__device__ inline unsigned int pkbf(float lo, float hi) {  // 2xf32 -> packed bf16
  unsigned int r;
  asm("v_cvt_pk_bf16_f32 %0, %1, %2" : "=v"(r) : "v"(lo), "v"(hi));
  return r;
}

// XCD-aware chunked swizzle (bijective: all our grids have nwg % 8 == 0).
// Dispatch round-robins linear ids over 8 XCDs; remap so each XCD works a
// contiguous tile chunk (A-panel L2 reuse).
__device__ inline void xcd_swz(int& bx, int& by) {
  const int nbx = gridDim.x;
  const int nwg = nbx * gridDim.y;
  int f = by * nbx + bx;
  f = (f & 7) * (nwg >> 3) + (f >> 3);
  bx = f % nbx;
  by = f / nbx;
}

// ---------------------------------------------------------------------------
// Cast + transpose:  W fp32 [R][ldW]  ->  Wt bf16 [ldW-cols][R]
// ---------------------------------------------------------------------------
__global__ __launch_bounds__(256) void transpose_cast(
    const float* __restrict__ W, unsigned short* __restrict__ Wt,
    int R, int ldW) {
  __shared__ unsigned short s[32 * 36];
  const int r0 = blockIdx.y * 32, c0 = blockIdx.x * 32;
  const int tr = threadIdx.x >> 3, tc = (threadIdx.x & 7) << 2;
  const float4 v = *(const float4*)(W + (size_t)(r0 + tr) * ldW + c0 + tc);
  s[tr * 36 + tc + 0] = f2b(v.x);
  s[tr * 36 + tc + 1] = f2b(v.y);
  s[tr * 36 + tc + 2] = f2b(v.z);
  s[tr * 36 + tc + 3] = f2b(v.w);
  __syncthreads();
  ushort4 o;
  o.x = s[(tc + 0) * 36 + tr];
  o.y = s[(tc + 1) * 36 + tr];
  o.z = s[(tc + 2) * 36 + tr];
  o.w = s[(tc + 3) * 36 + tr];
  *(ushort4*)(Wt + (size_t)(c0 + tr) * R + r0 + tc) = o;
}

// ---------------------------------------------------------------------------
// RMSNorm (one block per row of 2048) -> bf16.
// ---------------------------------------------------------------------------
__global__ __launch_bounds__(256) void rmsnorm(
    const float* __restrict__ X, const float* __restrict__ g,
    unsigned short* __restrict__ ob) {
  const int row = blockIdx.x;
  const float* x = X + (size_t)row * 2048;
  float ss = 0.f;
  for (int i = threadIdx.x; i < 2048; i += 256) { float v = x[i]; ss += v * v; }
  for (int off = 32; off; off >>= 1) ss += __shfl_down(ss, off, 64);
  __shared__ float red[4];
  if ((threadIdx.x & 63) == 0) red[threadIdx.x >> 6] = ss;
  __syncthreads();
  const float tot = red[0] + red[1] + red[2] + red[3];
  const float r = rsqrtf(tot * (1.f / 2048.f) + 1e-5f);
  for (int i = threadIdx.x; i < 2048; i += 256)
    ob[(size_t)row * 2048 + i] = f2b(x[i] * g[i] * r);
}

// ---------------------------------------------------------------------------
// out = x0 + b2f(h2), vectorized x4.  Pre-fill for the split-K down-proj.
// ---------------------------------------------------------------------------
__global__ __launch_bounds__(256) void add_res(
    const unsigned short* __restrict__ h2, const float* __restrict__ x,
    float* __restrict__ out) {
  const int i = blockIdx.x * 256 + threadIdx.x;
  const ushort4 h = ((const ushort4*)h2)[i];
  const float4 xv = ((const float4*)x)[i];
  float4 o;
  o.x = xv.x + b2f(h.x); o.y = xv.y + b2f(h.y);
  o.z = xv.z + b2f(h.z); o.w = xv.w + b2f(h.w);
  ((float4*)out)[i] = o;
}

// ---------------------------------------------------------------------------
// GEMM (128x128, 4 waves, 2 blocks/CU): QKV (epi 7), wo (epi 1), down (epi 8).
// ---------------------------------------------------------------------------
__global__ __launch_bounds__(256, 2) void gemm_bt(
    const unsigned short* __restrict__ A, const unsigned short* __restrict__ Bt,
    float* Cf, unsigned short* Cb,
    const unsigned short* add1b, const float* add2,
    int N, int Kfull, int Kchunk, int epi, int Tld,
    unsigned short* Cb2, unsigned short* Cb3) {
  __shared__ unsigned short As[128 * 64];
  __shared__ unsigned short Bs[128 * 64];
  const int tid = threadIdx.x;
  const int wave = tid >> 6, lane = tid & 63;
  const int quad = lane >> 4, l16 = lane & 15;
  int bx = blockIdx.x, by = blockIdx.y;
  xcd_swz(bx, by);
  const int m0 = by * 128, n0 = bx * 128;
  const int wr = (wave >> 1) * 64, wc = (wave & 1) * 64;
  const int Ks = blockIdx.z * Kchunk, Ke = Ks + Kchunk;

  f32x4 acc[4][4] = {};

  for (int k0 = Ks; k0 < Ke; k0 += 64) {
#pragma unroll
    for (int p = 0; p < 4; ++p) {
      const int idx = p * 256 + tid;
      const int row = idx >> 3;
      const int kc = ((idx & 7) ^ (row & 7)) * 8;
      const unsigned short* gA = A + (size_t)(m0 + row) * Kfull + k0 + kc;
      const unsigned short* gB = Bt + (size_t)(n0 + row) * Kfull + k0 + kc;
      unsigned short* lA = As + (size_t)(p * 256 + wave * 64) * 8;
      unsigned short* lB = Bs + (size_t)(p * 256 + wave * 64) * 8;
      __builtin_amdgcn_global_load_lds((gvoid_t*)gA, (lvoid_t*)lA, 16, 0, 0);
      __builtin_amdgcn_global_load_lds((gvoid_t*)gB, (lvoid_t*)lB, 16, 0, 0);
    }
    __syncthreads();

#pragma unroll
    for (int ks = 0; ks < 2; ++ks) {
      short8 af[4], bf[4];
#pragma unroll
      for (int i = 0; i < 4; ++i) {
        const int row = wr + i * 16 + l16;
        af[i] = *(const short8*)(As + row * 64 +
                                 (((ks << 2) | quad) ^ (row & 7)) * 8);
      }
#pragma unroll
      for (int j = 0; j < 4; ++j) {
        const int row = wc + j * 16 + l16;
        bf[j] = *(const short8*)(Bs + row * 64 +
                                 (((ks << 2) | quad) ^ (row & 7)) * 8);
      }
#pragma unroll
      for (int i = 0; i < 4; ++i)
#pragma unroll
        for (int j = 0; j < 4; ++j)
          acc[i][j] = __builtin_amdgcn_mfma_f32_16x16x32_bf16(
              af[i], bf[j], acc[i][j], 0, 0, 0);
    }
    __syncthreads();
  }

  if (epi == 7 && n0 >= 2560) {   // transposed V store (block-uniform)
#pragma unroll
    for (int i = 0; i < 4; ++i)
#pragma unroll
      for (int j = 0; j < 4; ++j) {
        const int row = m0 + wr + i * 16 + quad * 4;
        const int col = n0 + wc + j * 16 + l16 - 2560;
        ushort4 o;
        o.x = f2b(acc[i][j][0]); o.y = f2b(acc[i][j][1]);
        o.z = f2b(acc[i][j][2]); o.w = f2b(acc[i][j][3]);
        *(ushort4*)(Cb3 + (size_t)col * Tld + row) = o;
      }
    return;
  }

#pragma unroll
  for (int i = 0; i < 4; ++i)
#pragma unroll
    for (int j = 0; j < 4; ++j) {
      const int rowb = m0 + wr + i * 16 + quad * 4;
      const int col = n0 + wc + j * 16 + l16;
      float invf = 0.f, sgn = 0.f;
      if (epi == 7) {
        const int ip = (col & 63) >> 1;
        invf = __expf(-(float)ip * 0.28782313662f); // 10000^(-ip/32)
        sgn = (col & 1) ? 1.f : -1.f;
      }
#pragma unroll
      for (int r = 0; r < 4; ++r) {
        const size_t idx = (size_t)(rowb + r) * N + col;
        const float v = acc[i][j][r];
        const float p = __shfl_xor(v, 1, 64);
        if (epi == 1) {
          Cf[idx] = v + b2f(add1b[idx]);
        } else if (epi == 8) {
          atomicAdd(&Cf[idx], v);
        } else if (epi == 4) {
          Cb[idx] = f2b(v);
        } else if (epi == 3) {
          const float gt = b2f(add1b[idx]);
          Cb[idx] = f2b(gt / (1.f + __expf(-gt)) * v);
        } else {  // 7: rope -> q or k (block-uniform region)
          float sn, cs;
          __sincosf((float)(rowb + r) * invf, &sn, &cs);
          const unsigned short o = f2b(v * cs + sgn * p * sn);
          if (col < 2048)
            Cb[(size_t)(rowb + r) * 2048 + col] = o;
          else
            Cb2[(size_t)(rowb + r) * 512 + col - 2048] = o;
        }
      }
    }
}

// ---------------------------------------------------------------------------
// Fused gate+up GEMM: act = silu(A @ Wg^T) * (A @ Wu^T), bf16 out.
// Same 128^2 / BK=64 / 4-wave structure; 3 LDS panels (48 KB, 2 blocks/CU);
// A-fragments feed 2x MFMA (32 per K-step per wave); epilogue in-register.
// ---------------------------------------------------------------------------
__global__ __launch_bounds__(256, 2) void gemm_gu(
    const unsigned short* __restrict__ A, const unsigned short* __restrict__ Bg,
    const unsigned short* __restrict__ Bu, unsigned short* __restrict__ act,
    int N, int K) {
  __shared__ unsigned short As[128 * 64];
  __shared__ unsigned short Gs[128 * 64];
  __shared__ unsigned short Us[128 * 64];
  const int tid = threadIdx.x;
  const int wave = tid >> 6, lane = tid & 63;
  const int quad = lane >> 4, l16 = lane & 15;
  int bx = blockIdx.x, by = blockIdx.y;
  xcd_swz(bx, by);
  const int m0 = by * 128, n0 = bx * 128;
  const int wr = (wave >> 1) * 64, wc = (wave & 1) * 64;

  f32x4 aG[4][4] = {}, aU[4][4] = {};

  for (int k0 = 0; k0 < K; k0 += 64) {
#pragma unroll
    for (int p = 0; p < 4; ++p) {
      const int idx = p * 256 + tid;
      const int row = idx >> 3;
      const int kc = ((idx & 7) ^ (row & 7)) * 8;
      const size_t off = (size_t)(p * 256 + wave * 64) * 8;
      __builtin_amdgcn_global_load_lds(
          (gvoid_t*)(A + (size_t)(m0 + row) * K + k0 + kc),
          (lvoid_t*)(As + off), 16, 0, 0);
      __builtin_amdgcn_global_load_lds(
          (gvoid_t*)(Bg + (size_t)(n0 + row) * K + k0 + kc),
          (lvoid_t*)(Gs + off), 16, 0, 0);
      __builtin_amdgcn_global_load_lds(
          (gvoid_t*)(Bu + (size_t)(n0 + row) * K + k0 + kc),
          (lvoid_t*)(Us + off), 16, 0, 0);
    }
    __syncthreads();

#pragma unroll
    for (int ks = 0; ks < 2; ++ks) {
      short8 af[4], bg[4], bu[4];
#pragma unroll
      for (int i = 0; i < 4; ++i) {
        const int row = wr + i * 16 + l16;
        af[i] = *(const short8*)(As + row * 64 +
                                 (((ks << 2) | quad) ^ (row & 7)) * 8);
      }
#pragma unroll
      for (int j = 0; j < 4; ++j) {
        const int row = wc + j * 16 + l16;
        const int kk = (((ks << 2) | quad) ^ (row & 7)) * 8;
        bg[j] = *(const short8*)(Gs + row * 64 + kk);
        bu[j] = *(const short8*)(Us + row * 64 + kk);
      }
#pragma unroll
      for (int i = 0; i < 4; ++i)
#pragma unroll
        for (int j = 0; j < 4; ++j) {
          aG[i][j] = __builtin_amdgcn_mfma_f32_16x16x32_bf16(
              af[i], bg[j], aG[i][j], 0, 0, 0);
          aU[i][j] = __builtin_amdgcn_mfma_f32_16x16x32_bf16(
              af[i], bu[j], aU[i][j], 0, 0, 0);
        }
    }
    __syncthreads();
  }

  // Epilogue: act = silu(g) * u, straight from registers.
#pragma unroll
  for (int i = 0; i < 4; ++i)
#pragma unroll
    for (int j = 0; j < 4; ++j) {
      const int rowb = m0 + wr + i * 16 + quad * 4;
      const int col = n0 + wc + j * 16 + l16;
#pragma unroll
      for (int r = 0; r < 4; ++r) {
        const float g = aG[i][j][r], u = aU[i][j][r];
        act[(size_t)(rowb + r) * N + col] = f2b(g / (1.f + __expf(-g)) * u);
      }
    }
}

// ---------------------------------------------------------------------------
// Flash attention, swapped-QK^T 32x32x16 (unchanged from round 6).
// ---------------------------------------------------------------------------
__global__ __launch_bounds__(256) void flash_attn(
    const unsigned short* __restrict__ Qb, const unsigned short* __restrict__ Kb,
    const unsigned short* __restrict__ Vt, unsigned short* __restrict__ Y,
    int T) {
  const int tid = threadIdx.x;
  const int wave = tid >> 6, lane = tid & 63;
  const int l32 = lane & 31, hi = lane >> 5;
  const int h = blockIdx.y, kvh = h >> 2;
  const int qt = (blockIdx.x + wave * 16) << 5;
  const int qrow = qt + l32;

  short8 qf[4];
#pragma unroll
  for (int ds = 0; ds < 4; ++ds) {
    short8 v = *(const short8*)(Qb + (size_t)qrow * 2048 + h * 64 +
                                ds * 16 + hi * 8);
#pragma unroll
    for (int e = 0; e < 8; ++e)
      v[e] = (short)f2b(b2f((unsigned short)v[e]) * 0.125f);
    qf[ds] = v;
  }

  const unsigned short* Kp = Kb + (size_t)l32 * 512 + kvh * 64 + hi * 8;
  const unsigned short* Vp = Vt + (size_t)(kvh * 64 + l32) * T + hi * 8;

  const int niter = (qt >> 5) + 1;
  float m_i = -3e38f, l_i = 0.f;
  f32x16 o0 = {}, o1 = {};

  short8 kf[4], kfn[4];
#pragma unroll
  for (int ds = 0; ds < 4; ++ds) kf[ds] = *(const short8*)(Kp + ds * 16);

  for (int it = 0; it < niter; ++it) {
    const int k0 = it << 5;
    short8 vf[2][2];
#pragma unroll
    for (int dt = 0; dt < 2; ++dt)
#pragma unroll
      for (int ks = 0; ks < 2; ++ks)
        vf[dt][ks] =
            *(const short8*)(Vp + (size_t)dt * 32 * T + k0 + ks * 16);
    const int kn = (k0 + 32 < 2016) ? k0 + 32 : 2016;
#pragma unroll
    for (int ds = 0; ds < 4; ++ds)
      kfn[ds] = *(const short8*)(Kp + (size_t)kn * 512 + ds * 16);

    f32x16 S = {};
#pragma unroll
    for (int ds = 0; ds < 4; ++ds)
      S = __builtin_amdgcn_mfma_f32_32x32x16_bf16(kf[ds], qf[ds], S, 0, 0, 0);

    float s[16];
#pragma unroll
    for (int r = 0; r < 16; ++r) s[r] = S[r];
    if (k0 == qt) {
#pragma unroll
      for (int r = 0; r < 16; ++r)
        if (((r & 3) + 8 * (r >> 2) + 4 * hi) > l32) s[r] = -3e38f;
    }

    float tmax = s[0];
#pragma unroll
    for (int r = 1; r < 16; ++r) tmax = fmaxf(tmax, s[r]);
    tmax = fmaxf(tmax, __shfl_xor(tmax, 32, 64));

    if (!__all(tmax <= m_i + 8.f)) {
      const float mn = fmaxf(m_i, tmax);
      const float al = __expf(m_i - mn);
#pragma unroll
      for (int r = 0; r < 16; ++r) { o0[r] *= al; o1[r] *= al; }
      l_i *= al;
      m_i = mn;
    }

    float p[16], rs = 0.f;
#pragma unroll
    for (int r = 0; r < 16; ++r) { p[r] = __expf(s[r] - m_i); rs += p[r]; }
    rs += __shfl_xor(rs, 32, 64);
    l_i += rs;

    short8 pf[2];
#pragma unroll
    for (int ks = 0; ks < 2; ++ks) {
      const int rb = ks * 8;
      const unsigned int a0 = pkbf(p[rb + 0], p[rb + 1]);
      const unsigned int a1 = pkbf(p[rb + 2], p[rb + 3]);
      const unsigned int b0 = pkbf(p[rb + 4], p[rb + 5]);
      const unsigned int b1 = pkbf(p[rb + 6], p[rb + 7]);
      const unsigned int t0 = __shfl_xor((int)(hi ? a0 : b0), 32, 64);
      const unsigned int t1 = __shfl_xor((int)(hi ? a1 : b1), 32, 64);
      union { unsigned int u[4]; short8 v; } pu;
      pu.u[0] = hi ? t0 : a0;
      pu.u[1] = hi ? t1 : a1;
      pu.u[2] = hi ? b0 : t0;
      pu.u[3] = hi ? b1 : t1;
      pf[ks] = pu.v;
    }

#pragma unroll
    for (int ks = 0; ks < 2; ++ks) {
      o0 = __builtin_amdgcn_mfma_f32_32x32x16_bf16(vf[0][ks], pf[ks], o0,
                                                   0, 0, 0);
      o1 = __builtin_amdgcn_mfma_f32_32x32x16_bf16(vf[1][ks], pf[ks], o1,
                                                   0, 0, 0);
    }
#pragma unroll
    for (int ds = 0; ds < 4; ++ds) kf[ds] = kfn[ds];
  }

  const float inv = 1.f / l_i;
  unsigned short* Yp = Y + (size_t)qrow * 2048 + h * 64 + hi * 4;
#pragma unroll
  for (int g = 0; g < 4; ++g) {
    ushort4 u0, u1;
    u0.x = f2b(o0[g * 4 + 0] * inv); u0.y = f2b(o0[g * 4 + 1] * inv);
    u0.z = f2b(o0[g * 4 + 2] * inv); u0.w = f2b(o0[g * 4 + 3] * inv);
    *(ushort4*)(Yp + g * 8) = u0;
    u1.x = f2b(o1[g * 4 + 0] * inv); u1.y = f2b(o1[g * 4 + 1] * inv);
    u1.z = f2b(o1[g * 4 + 2] * inv); u1.w = f2b(o1[g * 4 + 3] * inv);
    *(ushort4*)(Yp + 32 + g * 8) = u1;
  }
}

// ---------------------------------------------------------------------------
extern "C" void kernel_launch(void* const* d_in, const int* in_sizes, int n_in,
                              void* d_out, int out_size, void* d_ws,
                              size_t ws_size, hipStream_t stream) {
  const float* x  = (const float*)d_in[0];
  const float* g1 = (const float*)d_in[1];
  const float* wq = (const float*)d_in[2];
  const float* wk = (const float*)d_in[3];
  const float* wv = (const float*)d_in[4];
  const float* wo = (const float*)d_in[5];
  const float* g2 = (const float*)d_in[6];
  const float* wg = (const float*)d_in[7];
  const float* wu = (const float*)d_in[8];
  const float* wd = (const float*)d_in[9];
  float* out = (float*)d_out;

  const int T = 2048, Dm = 2048, FF = 8192;
  char* ws = (char*)d_ws;
  const size_t MB = (size_t)1 << 20;

  unsigned short* wq_t = (unsigned short*)(ws + 0 * MB);    // 8 MB  } contig
  unsigned short* wk_t = (unsigned short*)(ws + 8 * MB);    // 2 MB  } rows
  unsigned short* wv_t = (unsigned short*)(ws + 10 * MB);   // 2 MB  } 0..3071
  unsigned short* wo_t = (unsigned short*)(ws + 12 * MB);   // 8 MB
  unsigned short* wg_t = (unsigned short*)(ws + 20 * MB);   // 32 MB
  unsigned short* wu_t = (unsigned short*)(ws + 52 * MB);   // 32 MB
  unsigned short* h1_b = (unsigned short*)(ws + 84 * MB);   // 8 MB
  unsigned short* h2_b = (unsigned short*)(ws + 92 * MB);   // 8 MB
  float*          x2_f = (float*)(ws + 100 * MB);           // 16 MB (dies early)
  unsigned short* gate = (unsigned short*)(ws + 100 * MB);  // 32 MB (act buf)
  unsigned short* q_b  = (unsigned short*)(ws + 132 * MB);  // 8 MB
  unsigned short* k_b  = (unsigned short*)(ws + 140 * MB);  // 2 MB
  unsigned short* vt_b = (unsigned short*)(ws + 142 * MB);  // 2 MB
  unsigned short* y_b  = (unsigned short*)(ws + 144 * MB);  // 8 MB
  unsigned short* wd_t = (unsigned short*)(ws + 132 * MB);  // 32 MB (after attn)

  // 1. Weight cast+transpose (wd deferred until attn scratch is dead).
  transpose_cast<<<dim3(64, 64), 256, 0, stream>>>(wq, wq_t, Dm, Dm);
  transpose_cast<<<dim3(16, 64), 256, 0, stream>>>(wk, wk_t, Dm, 512);
  transpose_cast<<<dim3(16, 64), 256, 0, stream>>>(wv, wv_t, Dm, 512);
  transpose_cast<<<dim3(64, 64), 256, 0, stream>>>(wo, wo_t, Dm, Dm);
  transpose_cast<<<dim3(256, 64), 256, 0, stream>>>(wg, wg_t, Dm, FF);
  transpose_cast<<<dim3(256, 64), 256, 0, stream>>>(wu, wu_t, Dm, FF);

  // 2. h1 = rms(x0)
  rmsnorm<<<T, 256, 0, stream>>>(x, g1, h1_b);

  // 3. Fused QKV projection (N=3072): rope q -> q_b, rope k -> k_b,
  //    transposed v -> vt_b.
  gemm_bt<<<dim3(24, 16), 256, 0, stream>>>(h1_b, wq_t, nullptr, q_b, nullptr,
                                            nullptr, 3072, Dm, Dm, 7, T, k_b,
                                            vt_b);

  // 4. Attention: 64 q-tiles x 32 heads, 4 independent waves/block.
  flash_attn<<<dim3(16, 32), 256, 0, stream>>>(q_b, k_b, vt_b, y_b, T);

  // 5. x2 = h1 + y @ wo  (epi 1).
  gemm_bt<<<dim3(16, 16), 256, 0, stream>>>(y_b, wo_t, x2_f, nullptr, h1_b,
                                            nullptr, Dm, Dm, Dm, 1, 0, nullptr,
                                            nullptr);

  // 6. wd transpose into the now-dead attention scratch.
  transpose_cast<<<dim3(64, 256), 256, 0, stream>>>(wd, wd_t, FF, Dm);

  // 7. h2 = rms(x2)
  rmsnorm<<<T, 256, 0, stream>>>(x2_f, g2, h2_b);

  // 8. MLP: fused gate+up (silu in-register), one dispatch.
  gemm_gu<<<dim3(64, 16), 256, 0, stream>>>(h2_b, wg_t, wu_t, gate, FF, Dm);

  // 9. out = h2 + x0 (pre-fill), then split-K x4 down-proj atomicAdd.
  add_res<<<(T * Dm / 4) / 256, 256, 0, stream>>>(h2_b, x, out);
  gemm_bt<<<dim3(16, 16, 4), 256, 0, stream>>>(gate, wd_t, out, nullptr,
                                               nullptr, nullptr, Dm, FF,
                                               FF / 4, 8, 0, nullptr, nullptr);
}

// Round 4
// 702.251 us; speedup vs baseline: 1.0968x; 1.0319x over previous
//
#include <hip/hip_runtime.h>
#include <cstdint>
#include <cstddef>

// ---------------------------------------------------------------------------
// Llama decoder layer, MI355X.  B=1, T=2048, D=2048, FF=8192, NH=32, NKV=8,
// HD=64.  bf16 MFMA, fp32 accumulate.
// out = h2 + mlp(h2) + x0, where h2 = rms(h1 + attn(h1)), h1 = rms(x0).
//
// Round 9: (a) xcd_part: weights-major XCD partition (by cycles fastest) —
// round-8's swizzle was A-major and made each XCD stream all 64 MB of
// weights (FETCH 528 MB vs 72 unique).  (b) wo split-K x2 (was 1 block/CU,
// no partner to hide the barrier drain).  (c) down-proj split-K 4 -> 2
// (same 2 blocks/CU, half the atomics).
// ---------------------------------------------------------------------------

typedef __attribute__((ext_vector_type(8))) short short8;   // 8 x bf16
typedef __attribute__((ext_vector_type(4))) float f32x4;
typedef __attribute__((ext_vector_type(16))) float f32x16;

typedef __attribute__((address_space(1))) const void gvoid_t;  // global
typedef __attribute__((address_space(3))) void lvoid_t;        // LDS

__device__ inline unsigned short f2b(float f) {   // fp32 -> bf16 (RNE)
  unsigned int u = __float_as_uint(f);
  u += 0x7fffu + ((u >> 16) & 1u);
  return (unsigned short)(u >> 16);
}
__device__ inline float b2f(unsigned short s) {
  return __uint_as_float((unsigned int)s << 16);
}
__device__ inline unsigned int pkbf(float lo, float hi) {  // 2xf32 -> packed bf16
  unsigned int r;
  asm("v_cvt_pk_bf16_f32 %0, %1, %2" : "=v"(r) : "v"(lo), "v"(hi));
  return r;
}

// Weights-major XCD partition (requires gridDim.x % 8 == 0; z-safe since
// per-z block count is a multiple of 8).  XCD k owns bx-chunk
// [k*cpx, (k+1)*cpx), by cycles fastest -> co-resident blocks on one XCD
// share a few weight panels (L2) while A panels come from L3.
__device__ inline void xcd_part(int& bx, int& by) {
  const int nbx = gridDim.x, nby = gridDim.y;
  const int cpx = nbx >> 3;
  const int f = by * nbx + bx;
  const int xcd = f & 7;
  const int t = f >> 3;
  bx = xcd * cpx + t / nby;
  by = t % nby;
}

// ---------------------------------------------------------------------------
// Cast + transpose:  W fp32 [R][ldW]  ->  Wt bf16 [ldW-cols][R]
// ---------------------------------------------------------------------------
__global__ __launch_bounds__(256) void transpose_cast(
    const float* __restrict__ W, unsigned short* __restrict__ Wt,
    int R, int ldW) {
  __shared__ unsigned short s[32 * 36];
  const int r0 = blockIdx.y * 32, c0 = blockIdx.x * 32;
  const int tr = threadIdx.x >> 3, tc = (threadIdx.x & 7) << 2;
  const float4 v = *(const float4*)(W + (size_t)(r0 + tr) * ldW + c0 + tc);
  s[tr * 36 + tc + 0] = f2b(v.x);
  s[tr * 36 + tc + 1] = f2b(v.y);
  s[tr * 36 + tc + 2] = f2b(v.z);
  s[tr * 36 + tc + 3] = f2b(v.w);
  __syncthreads();
  ushort4 o;
  o.x = s[(tc + 0) * 36 + tr];
  o.y = s[(tc + 1) * 36 + tr];
  o.z = s[(tc + 2) * 36 + tr];
  o.w = s[(tc + 3) * 36 + tr];
  *(ushort4*)(Wt + (size_t)(c0 + tr) * R + r0 + tc) = o;
}

// ---------------------------------------------------------------------------
// RMSNorm (one block per row of 2048) -> bf16.
// ---------------------------------------------------------------------------
__global__ __launch_bounds__(256) void rmsnorm(
    const float* __restrict__ X, const float* __restrict__ g,
    unsigned short* __restrict__ ob) {
  const int row = blockIdx.x;
  const float* x = X + (size_t)row * 2048;
  float ss = 0.f;
  for (int i = threadIdx.x; i < 2048; i += 256) { float v = x[i]; ss += v * v; }
  for (int off = 32; off; off >>= 1) ss += __shfl_down(ss, off, 64);
  __shared__ float red[4];
  if ((threadIdx.x & 63) == 0) red[threadIdx.x >> 6] = ss;
  __syncthreads();
  const float tot = red[0] + red[1] + red[2] + red[3];
  const float r = rsqrtf(tot * (1.f / 2048.f) + 1e-5f);
  for (int i = threadIdx.x; i < 2048; i += 256)
    ob[(size_t)row * 2048 + i] = f2b(x[i] * g[i] * r);
}

// ---------------------------------------------------------------------------
// out = x0 + b2f(h2), vectorized x4.  Pre-fill for the split-K down-proj.
// ---------------------------------------------------------------------------
__global__ __launch_bounds__(256) void add_res(
    const unsigned short* __restrict__ h2, const float* __restrict__ x,
    float* __restrict__ out) {
  const int i = blockIdx.x * 256 + threadIdx.x;
  const ushort4 h = ((const ushort4*)h2)[i];
  const float4 xv = ((const float4*)x)[i];
  float4 o;
  o.x = xv.x + b2f(h.x); o.y = xv.y + b2f(h.y);
  o.z = xv.z + b2f(h.z); o.w = xv.w + b2f(h.w);
  ((float4*)out)[i] = o;
}

// out = b2f(h1), pre-fill for the split-K wo projection.
__global__ __launch_bounds__(256) void prefill_b2f(
    const unsigned short* __restrict__ h, float* __restrict__ out) {
  const int i = blockIdx.x * 256 + threadIdx.x;
  const ushort4 v = ((const ushort4*)h)[i];
  float4 o;
  o.x = b2f(v.x); o.y = b2f(v.y); o.z = b2f(v.z); o.w = b2f(v.w);
  ((float4*)out)[i] = o;
}

// ---------------------------------------------------------------------------
// GEMM (128x128, 4 waves, 2 blocks/CU): QKV (epi 7), wo/down (epi 8).
// ---------------------------------------------------------------------------
__global__ __launch_bounds__(256, 2) void gemm_bt(
    const unsigned short* __restrict__ A, const unsigned short* __restrict__ Bt,
    float* Cf, unsigned short* Cb,
    const unsigned short* add1b, const float* add2,
    int N, int Kfull, int Kchunk, int epi, int Tld,
    unsigned short* Cb2, unsigned short* Cb3) {
  __shared__ unsigned short As[128 * 64];
  __shared__ unsigned short Bs[128 * 64];
  const int tid = threadIdx.x;
  const int wave = tid >> 6, lane = tid & 63;
  const int quad = lane >> 4, l16 = lane & 15;
  int bx = blockIdx.x, by = blockIdx.y;
  xcd_part(bx, by);
  const int m0 = by * 128, n0 = bx * 128;
  const int wr = (wave >> 1) * 64, wc = (wave & 1) * 64;
  const int Ks = blockIdx.z * Kchunk, Ke = Ks + Kchunk;

  f32x4 acc[4][4] = {};

  for (int k0 = Ks; k0 < Ke; k0 += 64) {
#pragma unroll
    for (int p = 0; p < 4; ++p) {
      const int idx = p * 256 + tid;
      const int row = idx >> 3;
      const int kc = ((idx & 7) ^ (row & 7)) * 8;
      const unsigned short* gA = A + (size_t)(m0 + row) * Kfull + k0 + kc;
      const unsigned short* gB = Bt + (size_t)(n0 + row) * Kfull + k0 + kc;
      unsigned short* lA = As + (size_t)(p * 256 + wave * 64) * 8;
      unsigned short* lB = Bs + (size_t)(p * 256 + wave * 64) * 8;
      __builtin_amdgcn_global_load_lds((gvoid_t*)gA, (lvoid_t*)lA, 16, 0, 0);
      __builtin_amdgcn_global_load_lds((gvoid_t*)gB, (lvoid_t*)lB, 16, 0, 0);
    }
    __syncthreads();

#pragma unroll
    for (int ks = 0; ks < 2; ++ks) {
      short8 af[4], bf[4];
#pragma unroll
      for (int i = 0; i < 4; ++i) {
        const int row = wr + i * 16 + l16;
        af[i] = *(const short8*)(As + row * 64 +
                                 (((ks << 2) | quad) ^ (row & 7)) * 8);
      }
#pragma unroll
      for (int j = 0; j < 4; ++j) {
        const int row = wc + j * 16 + l16;
        bf[j] = *(const short8*)(Bs + row * 64 +
                                 (((ks << 2) | quad) ^ (row & 7)) * 8);
      }
#pragma unroll
      for (int i = 0; i < 4; ++i)
#pragma unroll
        for (int j = 0; j < 4; ++j)
          acc[i][j] = __builtin_amdgcn_mfma_f32_16x16x32_bf16(
              af[i], bf[j], acc[i][j], 0, 0, 0);
    }
    __syncthreads();
  }

  if (epi == 7 && n0 >= 2560) {   // transposed V store (block-uniform)
#pragma unroll
    for (int i = 0; i < 4; ++i)
#pragma unroll
      for (int j = 0; j < 4; ++j) {
        const int row = m0 + wr + i * 16 + quad * 4;
        const int col = n0 + wc + j * 16 + l16 - 2560;
        ushort4 o;
        o.x = f2b(acc[i][j][0]); o.y = f2b(acc[i][j][1]);
        o.z = f2b(acc[i][j][2]); o.w = f2b(acc[i][j][3]);
        *(ushort4*)(Cb3 + (size_t)col * Tld + row) = o;
      }
    return;
  }

#pragma unroll
  for (int i = 0; i < 4; ++i)
#pragma unroll
    for (int j = 0; j < 4; ++j) {
      const int rowb = m0 + wr + i * 16 + quad * 4;
      const int col = n0 + wc + j * 16 + l16;
      float invf = 0.f, sgn = 0.f;
      if (epi == 7) {
        const int ip = (col & 63) >> 1;
        invf = __expf(-(float)ip * 0.28782313662f); // 10000^(-ip/32)
        sgn = (col & 1) ? 1.f : -1.f;
      }
#pragma unroll
      for (int r = 0; r < 4; ++r) {
        const size_t idx = (size_t)(rowb + r) * N + col;
        const float v = acc[i][j][r];
        const float p = __shfl_xor(v, 1, 64);
        if (epi == 1) {
          Cf[idx] = v + b2f(add1b[idx]);
        } else if (epi == 8) {
          atomicAdd(&Cf[idx], v);
        } else {  // 7: rope -> q or k (block-uniform region)
          float sn, cs;
          __sincosf((float)(rowb + r) * invf, &sn, &cs);
          const unsigned short o = f2b(v * cs + sgn * p * sn);
          if (col < 2048)
            Cb[(size_t)(rowb + r) * 2048 + col] = o;
          else
            Cb2[(size_t)(rowb + r) * 512 + col - 2048] = o;
        }
      }
    }
}

// ---------------------------------------------------------------------------
// Fused gate+up GEMM: act = silu(A @ Wg^T) * (A @ Wu^T), bf16 out.
// 128^2 / BK=64 / 4-wave; 3 LDS panels (48 KB, 2 blocks/CU).
// ---------------------------------------------------------------------------
__global__ __launch_bounds__(256, 2) void gemm_gu(
    const unsigned short* __restrict__ A, const unsigned short* __restrict__ Bg,
    const unsigned short* __restrict__ Bu, unsigned short* __restrict__ act,
    int N, int K) {
  __shared__ unsigned short As[128 * 64];
  __shared__ unsigned short Gs[128 * 64];
  __shared__ unsigned short Us[128 * 64];
  const int tid = threadIdx.x;
  const int wave = tid >> 6, lane = tid & 63;
  const int quad = lane >> 4, l16 = lane & 15;
  int bx = blockIdx.x, by = blockIdx.y;
  xcd_part(bx, by);
  const int m0 = by * 128, n0 = bx * 128;
  const int wr = (wave >> 1) * 64, wc = (wave & 1) * 64;

  f32x4 aG[4][4] = {}, aU[4][4] = {};

  for (int k0 = 0; k0 < K; k0 += 64) {
#pragma unroll
    for (int p = 0; p < 4; ++p) {
      const int idx = p * 256 + tid;
      const int row = idx >> 3;
      const int kc = ((idx & 7) ^ (row & 7)) * 8;
      const size_t off = (size_t)(p * 256 + wave * 64) * 8;
      __builtin_amdgcn_global_load_lds(
          (gvoid_t*)(A + (size_t)(m0 + row) * K + k0 + kc),
          (lvoid_t*)(As + off), 16, 0, 0);
      __builtin_amdgcn_global_load_lds(
          (gvoid_t*)(Bg + (size_t)(n0 + row) * K + k0 + kc),
          (lvoid_t*)(Gs + off), 16, 0, 0);
      __builtin_amdgcn_global_load_lds(
          (gvoid_t*)(Bu + (size_t)(n0 + row) * K + k0 + kc),
          (lvoid_t*)(Us + off), 16, 0, 0);
    }
    __syncthreads();

#pragma unroll
    for (int ks = 0; ks < 2; ++ks) {
      short8 af[4], bg[4], bu[4];
#pragma unroll
      for (int i = 0; i < 4; ++i) {
        const int row = wr + i * 16 + l16;
        af[i] = *(const short8*)(As + row * 64 +
                                 (((ks << 2) | quad) ^ (row & 7)) * 8);
      }
#pragma unroll
      for (int j = 0; j < 4; ++j) {
        const int row = wc + j * 16 + l16;
        const int kk = (((ks << 2) | quad) ^ (row & 7)) * 8;
        bg[j] = *(const short8*)(Gs + row * 64 + kk);
        bu[j] = *(const short8*)(Us + row * 64 + kk);
      }
#pragma unroll
      for (int i = 0; i < 4; ++i)
#pragma unroll
        for (int j = 0; j < 4; ++j) {
          aG[i][j] = __builtin_amdgcn_mfma_f32_16x16x32_bf16(
              af[i], bg[j], aG[i][j], 0, 0, 0);
          aU[i][j] = __builtin_amdgcn_mfma_f32_16x16x32_bf16(
              af[i], bu[j], aU[i][j], 0, 0, 0);
        }
    }
    __syncthreads();
  }

  // Epilogue: act = silu(g) * u, straight from registers.
#pragma unroll
  for (int i = 0; i < 4; ++i)
#pragma unroll
    for (int j = 0; j < 4; ++j) {
      const int rowb = m0 + wr + i * 16 + quad * 4;
      const int col = n0 + wc + j * 16 + l16;
#pragma unroll
      for (int r = 0; r < 4; ++r) {
        const float g = aG[i][j][r], u = aU[i][j][r];
        act[(size_t)(rowb + r) * N + col] = f2b(g / (1.f + __expf(-g)) * u);
      }
    }
}

// ---------------------------------------------------------------------------
// Flash attention, swapped-QK^T 32x32x16 (unchanged from round 6).
// ---------------------------------------------------------------------------
__global__ __launch_bounds__(256) void flash_attn(
    const unsigned short* __restrict__ Qb, const unsigned short* __restrict__ Kb,
    const unsigned short* __restrict__ Vt, unsigned short* __restrict__ Y,
    int T) {
  const int tid = threadIdx.x;
  const int wave = tid >> 6, lane = tid & 63;
  const int l32 = lane & 31, hi = lane >> 5;
  const int h = blockIdx.y, kvh = h >> 2;
  const int qt = (blockIdx.x + wave * 16) << 5;
  const int qrow = qt + l32;

  short8 qf[4];
#pragma unroll
  for (int ds = 0; ds < 4; ++ds) {
    short8 v = *(const short8*)(Qb + (size_t)qrow * 2048 + h * 64 +
                                ds * 16 + hi * 8);
#pragma unroll
    for (int e = 0; e < 8; ++e)
      v[e] = (short)f2b(b2f((unsigned short)v[e]) * 0.125f);
    qf[ds] = v;
  }

  const unsigned short* Kp = Kb + (size_t)l32 * 512 + kvh * 64 + hi * 8;
  const unsigned short* Vp = Vt + (size_t)(kvh * 64 + l32) * T + hi * 8;

  const int niter = (qt >> 5) + 1;
  float m_i = -3e38f, l_i = 0.f;
  f32x16 o0 = {}, o1 = {};

  short8 kf[4], kfn[4];
#pragma unroll
  for (int ds = 0; ds < 4; ++ds) kf[ds] = *(const short8*)(Kp + ds * 16);

  for (int it = 0; it < niter; ++it) {
    const int k0 = it << 5;
    short8 vf[2][2];
#pragma unroll
    for (int dt = 0; dt < 2; ++dt)
#pragma unroll
      for (int ks = 0; ks < 2; ++ks)
        vf[dt][ks] =
            *(const short8*)(Vp + (size_t)dt * 32 * T + k0 + ks * 16);
    const int kn = (k0 + 32 < 2016) ? k0 + 32 : 2016;
#pragma unroll
    for (int ds = 0; ds < 4; ++ds)
      kfn[ds] = *(const short8*)(Kp + (size_t)kn * 512 + ds * 16);

    f32x16 S = {};
#pragma unroll
    for (int ds = 0; ds < 4; ++ds)
      S = __builtin_amdgcn_mfma_f32_32x32x16_bf16(kf[ds], qf[ds], S, 0, 0, 0);

    float s[16];
#pragma unroll
    for (int r = 0; r < 16; ++r) s[r] = S[r];
    if (k0 == qt) {
#pragma unroll
      for (int r = 0; r < 16; ++r)
        if (((r & 3) + 8 * (r >> 2) + 4 * hi) > l32) s[r] = -3e38f;
    }

    float tmax = s[0];
#pragma unroll
    for (int r = 1; r < 16; ++r) tmax = fmaxf(tmax, s[r]);
    tmax = fmaxf(tmax, __shfl_xor(tmax, 32, 64));

    if (!__all(tmax <= m_i + 8.f)) {
      const float mn = fmaxf(m_i, tmax);
      const float al = __expf(m_i - mn);
#pragma unroll
      for (int r = 0; r < 16; ++r) { o0[r] *= al; o1[r] *= al; }
      l_i *= al;
      m_i = mn;
    }

    float p[16], rs = 0.f;
#pragma unroll
    for (int r = 0; r < 16; ++r) { p[r] = __expf(s[r] - m_i); rs += p[r]; }
    rs += __shfl_xor(rs, 32, 64);
    l_i += rs;

    short8 pf[2];
#pragma unroll
    for (int ks = 0; ks < 2; ++ks) {
      const int rb = ks * 8;
      const unsigned int a0 = pkbf(p[rb + 0], p[rb + 1]);
      const unsigned int a1 = pkbf(p[rb + 2], p[rb + 3]);
      const unsigned int b0 = pkbf(p[rb + 4], p[rb + 5]);
      const unsigned int b1 = pkbf(p[rb + 6], p[rb + 7]);
      const unsigned int t0 = __shfl_xor((int)(hi ? a0 : b0), 32, 64);
      const unsigned int t1 = __shfl_xor((int)(hi ? a1 : b1), 32, 64);
      union { unsigned int u[4]; short8 v; } pu;
      pu.u[0] = hi ? t0 : a0;
      pu.u[1] = hi ? t1 : a1;
      pu.u[2] = hi ? b0 : t0;
      pu.u[3] = hi ? b1 : t1;
      pf[ks] = pu.v;
    }

#pragma unroll
    for (int ks = 0; ks < 2; ++ks) {
      o0 = __builtin_amdgcn_mfma_f32_32x32x16_bf16(vf[0][ks], pf[ks], o0,
                                                   0, 0, 0);
      o1 = __builtin_amdgcn_mfma_f32_32x32x16_bf16(vf[1][ks], pf[ks], o1,
                                                   0, 0, 0);
    }
#pragma unroll
    for (int ds = 0; ds < 4; ++ds) kf[ds] = kfn[ds];
  }

  const float inv = 1.f / l_i;
  unsigned short* Yp = Y + (size_t)qrow * 2048 + h * 64 + hi * 4;
#pragma unroll
  for (int g = 0; g < 4; ++g) {
    ushort4 u0, u1;
    u0.x = f2b(o0[g * 4 + 0] * inv); u0.y = f2b(o0[g * 4 + 1] * inv);
    u0.z = f2b(o0[g * 4 + 2] * inv); u0.w = f2b(o0[g * 4 + 3] * inv);
    *(ushort4*)(Yp + g * 8) = u0;
    u1.x = f2b(o1[g * 4 + 0] * inv); u1.y = f2b(o1[g * 4 + 1] * inv);
    u1.z = f2b(o1[g * 4 + 2] * inv); u1.w = f2b(o1[g * 4 + 3] * inv);
    *(ushort4*)(Yp + 32 + g * 8) = u1;
  }
}

// ---------------------------------------------------------------------------
extern "C" void kernel_launch(void* const* d_in, const int* in_sizes, int n_in,
                              void* d_out, int out_size, void* d_ws,
                              size_t ws_size, hipStream_t stream) {
  const float* x  = (const float*)d_in[0];
  const float* g1 = (const float*)d_in[1];
  const float* wq = (const float*)d_in[2];
  const float* wk = (const float*)d_in[3];
  const float* wv = (const float*)d_in[4];
  const float* wo = (const float*)d_in[5];
  const float* g2 = (const float*)d_in[6];
  const float* wg = (const float*)d_in[7];
  const float* wu = (const float*)d_in[8];
  const float* wd = (const float*)d_in[9];
  float* out = (float*)d_out;

  const int T = 2048, Dm = 2048, FF = 8192;
  char* ws = (char*)d_ws;
  const size_t MB = (size_t)1 << 20;

  unsigned short* wq_t = (unsigned short*)(ws + 0 * MB);    // 8 MB  } contig
  unsigned short* wk_t = (unsigned short*)(ws + 8 * MB);    // 2 MB  } rows
  unsigned short* wv_t = (unsigned short*)(ws + 10 * MB);   // 2 MB  } 0..3071
  unsigned short* wo_t = (unsigned short*)(ws + 12 * MB);   // 8 MB
  unsigned short* wg_t = (unsigned short*)(ws + 20 * MB);   // 32 MB
  unsigned short* wu_t = (unsigned short*)(ws + 52 * MB);   // 32 MB
  unsigned short* h1_b = (unsigned short*)(ws + 84 * MB);   // 8 MB
  unsigned short* h2_b = (unsigned short*)(ws + 92 * MB);   // 8 MB
  float*          x2_f = (float*)(ws + 100 * MB);           // 16 MB (dies early)
  unsigned short* gate = (unsigned short*)(ws + 100 * MB);  // 32 MB (act buf)
  unsigned short* q_b  = (unsigned short*)(ws + 132 * MB);  // 8 MB
  unsigned short* k_b  = (unsigned short*)(ws + 140 * MB);  // 2 MB
  unsigned short* vt_b = (unsigned short*)(ws + 142 * MB);  // 2 MB
  unsigned short* y_b  = (unsigned short*)(ws + 144 * MB);  // 8 MB
  unsigned short* wd_t = (unsigned short*)(ws + 132 * MB);  // 32 MB (after attn)

  // 1. Weight cast+transpose (wd deferred until attn scratch is dead).
  transpose_cast<<<dim3(64, 64), 256, 0, stream>>>(wq, wq_t, Dm, Dm);
  transpose_cast<<<dim3(16, 64), 256, 0, stream>>>(wk, wk_t, Dm, 512);
  transpose_cast<<<dim3(16, 64), 256, 0, stream>>>(wv, wv_t, Dm, 512);
  transpose_cast<<<dim3(64, 64), 256, 0, stream>>>(wo, wo_t, Dm, Dm);
  transpose_cast<<<dim3(256, 64), 256, 0, stream>>>(wg, wg_t, Dm, FF);
  transpose_cast<<<dim3(256, 64), 256, 0, stream>>>(wu, wu_t, Dm, FF);

  // 2. h1 = rms(x0)
  rmsnorm<<<T, 256, 0, stream>>>(x, g1, h1_b);

  // 3. Fused QKV projection (N=3072): rope q -> q_b, rope k -> k_b,
  //    transposed v -> vt_b.
  gemm_bt<<<dim3(24, 16), 256, 0, stream>>>(h1_b, wq_t, nullptr, q_b, nullptr,
                                            nullptr, 3072, Dm, Dm, 7, T, k_b,
                                            vt_b);

  // 4. Attention: 64 q-tiles x 32 heads, 4 independent waves/block.
  flash_attn<<<dim3(16, 32), 256, 0, stream>>>(q_b, k_b, vt_b, y_b, T);

  // 5. x2 = h1 + y @ wo, split-K x2 (prefill h1, then atomicAdd partials).
  prefill_b2f<<<(T * Dm / 4) / 256, 256, 0, stream>>>(h1_b, x2_f);
  gemm_bt<<<dim3(16, 16, 2), 256, 0, stream>>>(y_b, wo_t, x2_f, nullptr,
                                               nullptr, nullptr, Dm, Dm,
                                               Dm / 2, 8, 0, nullptr, nullptr);

  // 6. wd transpose into the now-dead attention scratch.
  transpose_cast<<<dim3(64, 256), 256, 0, stream>>>(wd, wd_t, FF, Dm);

  // 7. h2 = rms(x2)
  rmsnorm<<<T, 256, 0, stream>>>(x2_f, g2, h2_b);

  // 8. MLP: fused gate+up (silu in-register), one dispatch.
  gemm_gu<<<dim3(64, 16), 256, 0, stream>>>(h2_b, wg_t, wu_t, gate, FF, Dm);

  // 9. out = h2 + x0 (pre-fill), then split-K x2 down-proj atomicAdd.
  add_res<<<(T * Dm / 4) / 256, 256, 0, stream>>>(h2_b, x, out);
  gemm_bt<<<dim3(16, 16, 2), 256, 0, stream>>>(gate, wd_t, out, nullptr,
                                               nullptr, nullptr, Dm, FF,
                                               FF / 2, 8, 0, nullptr, nullptr);
}